// Round 6
// baseline (144.674 us; speedup 1.0000x reference)
//
#include <hip/hip_runtime.h>

#define N_NODES 10000
#define E_EDGES 320000
#define D 256
#define LRELU_ALPHA 0.2f

// All float tensors fp32 (established round 3). Edges int32-or-int64 detect.

constexpr int GR = 16;       // GEMM rows per block (10000 / 16 = 625 exact)
constexpr int XSTRIDE = 20;  // xs row stride in floats: 80 B = 5*16 B (b128-aligned)

// ---------------------------------------------------------------------------
// K1: raw edges -> dst[] and CSR row_start[] in one pass. src is sorted.
// ---------------------------------------------------------------------------
__global__ __launch_bounds__(256) void prep(const int* __restrict__ raw,
                                            int* __restrict__ dst,
                                            int* __restrict__ row_start) {
    bool is64 = true;  // int64 rows: [s_lo, s_hi, d_lo, d_hi], hi words == 0
    #pragma unroll
    for (int t = 0; t < 16; ++t)
        if (raw[2 * t + 1] != 0) is64 = false;

    int e = blockIdx.x * 256 + threadIdx.x;
    if (e >= E_EDGES) return;
    int s, d, sprev;
    if (is64) { s = raw[4 * e]; d = raw[4 * e + 2]; sprev = e ? raw[4 * e - 4] : -1; }
    else      { s = raw[2 * e]; d = raw[2 * e + 1]; sprev = e ? raw[2 * e - 2] : -1; }
    dst[e] = d;
    for (int r = sprev + 1; r <= s; ++r) row_start[r] = e;
    if (e == E_EDGES - 1)
        for (int r = s + 1; r <= N_NODES; ++r) row_start[r] = E_EDGES;
}

// ---------------------------------------------------------------------------
// K2: feats = X @ W1 + b1 (fp32), fused a_src/a_dst row-dots.
// Block: 16 rows x 256 cols, thread j = col j. X tile staged k-major in LDS.
// W1 consumed via 8-deep register prefetch: the 8 loads for tile k0+8 are in
// flight during the 128 FMAs of tile k0 (~256 cyc issue > ~200 cyc L2 hit
// latency) -> latency hidden by ILP even at 2.4 blocks/CU occupancy.
// ---------------------------------------------------------------------------
__global__ __launch_bounds__(256) void gemm_rowdots(const float* __restrict__ X,
                                                    const float* __restrict__ W1,
                                                    const float* __restrict__ b1,
                                                    const float* __restrict__ Wa,
                                                    float* __restrict__ feats,
                                                    float* __restrict__ a_src,
                                                    float* __restrict__ a_dst) {
    __shared__ float xs[D][XSTRIDE];
    __shared__ float red[2][4][GR];  // [dot][wave][row]
    const int j = threadIdx.x;
    const int row0 = blockIdx.x * GR;

    // stage: thread (r = j&15, c4b = j>>4) loads 4 float4s of row r
    {
        const int r = j & 15, c4b = j >> 4;
        const float4* X4 = (const float4*)(X + (size_t)(row0 + r) * D);
        #pragma unroll
        for (int h = 0; h < 4; ++h) {
            const int c4 = c4b + 16 * h;  // [0,64)
            float4 v = X4[c4];
            xs[4 * c4 + 0][r] = v.x;
            xs[4 * c4 + 1][r] = v.y;
            xs[4 * c4 + 2][r] = v.z;
            xs[4 * c4 + 3][r] = v.w;
        }
    }
    __syncthreads();

    float acc[GR];
    #pragma unroll
    for (int r = 0; r < GR; ++r) acc[r] = 0.f;

    float wbuf[8], wnext[8];
    #pragma unroll
    for (int u = 0; u < 8; ++u) wbuf[u] = W1[u * D + j];

    for (int k0 = 0; k0 < D; k0 += 8) {
        const int kn = k0 + 8;
        if (kn < D) {
            #pragma unroll
            for (int u = 0; u < 8; ++u) wnext[u] = W1[(kn + u) * D + j];
        }
        #pragma unroll
        for (int u = 0; u < 8; ++u) {
            const int k = k0 + u;
            const float w = wbuf[u];
            const float4 x0 = *(const float4*)&xs[k][0];
            const float4 x1 = *(const float4*)&xs[k][4];
            const float4 x2 = *(const float4*)&xs[k][8];
            const float4 x3 = *(const float4*)&xs[k][12];
            acc[0]  += x0.x * w; acc[1]  += x0.y * w; acc[2]  += x0.z * w; acc[3]  += x0.w * w;
            acc[4]  += x1.x * w; acc[5]  += x1.y * w; acc[6]  += x1.z * w; acc[7]  += x1.w * w;
            acc[8]  += x2.x * w; acc[9]  += x2.y * w; acc[10] += x2.z * w; acc[11] += x2.w * w;
            acc[12] += x3.x * w; acc[13] += x3.y * w; acc[14] += x3.z * w; acc[15] += x3.w * w;
        }
        if (kn < D) {
            #pragma unroll
            for (int u = 0; u < 8; ++u) wbuf[u] = wnext[u];
        }
    }

    const float bias = b1[j];
    const float wa1 = Wa[j], wa2 = Wa[D + j];
    #pragma unroll
    for (int r = 0; r < GR; ++r) acc[r] += bias;
    #pragma unroll
    for (int r = 0; r < GR; ++r) feats[(size_t)(row0 + r) * D + j] = acc[r];

    // fused row-dots: each lane holds a DISTINCT column partial -> reduce needed
    const int lane = j & 63, wv = j >> 6;
    #pragma unroll
    for (int r = 0; r < GR; ++r) {
        float p1 = acc[r] * wa1;
        float p2 = acc[r] * wa2;
        #pragma unroll
        for (int off = 32; off > 0; off >>= 1) {
            p1 += __shfl_down(p1, off);
            p2 += __shfl_down(p2, off);
        }
        if (lane == 0) { red[0][wv][r] = p1; red[1][wv][r] = p2; }
    }
    __syncthreads();
    if (j < 2 * GR) {
        const int dot = j >> 4, r = j & 15;
        float s = red[dot][0][r] + red[dot][1][r] + red[dot][2][r] + red[dot][3][r];
        (dot == 0 ? a_src : a_dst)[row0 + r] = s;
    }
}

// ---------------------------------------------------------------------------
// K3: one WAVE per node (4 nodes per block). Lane l owns cols 4l..4l+3
// (float4 gather, 1 KB per wave-instruction). All lanes walk the same edge
// list, so dsum and the final scale are wave-uniform by construction: no
// lane reduce, no LDS, no __syncthreads, direct float4 store.
// ---------------------------------------------------------------------------
__global__ __launch_bounds__(256) void aggregate(const int* __restrict__ dst,
                                                 const int* __restrict__ row_start,
                                                 const float* __restrict__ a_src,
                                                 const float* __restrict__ a_dst,
                                                 const float* __restrict__ ba,
                                                 const float* __restrict__ feats,
                                                 float* __restrict__ out) {
    const int i = blockIdx.x * 4 + (threadIdx.x >> 6);  // N_NODES % 4 == 0
    const int l = threadIdx.x & 63;
    const int rs = row_start[i], re = row_start[i + 1];
    const float base = a_src[i] + ba[0];
    const float4* F4 = (const float4*)feats;

    float4 acc = {0.f, 0.f, 0.f, 0.f};
    float dsum = 0.f;

    int e = rs;
    for (; e + 4 <= re; e += 4) {  // 4 independent gathers in flight
        const int d0 = dst[e], d1 = dst[e + 1], d2 = dst[e + 2], d3 = dst[e + 3];
        const float4 f0 = F4[(size_t)d0 * 64 + l];
        const float4 f1 = F4[(size_t)d1 * 64 + l];
        const float4 f2 = F4[(size_t)d2 * 64 + l];
        const float4 f3 = F4[(size_t)d3 * 64 + l];
        float s0 = base + a_dst[d0]; s0 = (s0 > 0.f) ? s0 : LRELU_ALPHA * s0;
        float s1 = base + a_dst[d1]; s1 = (s1 > 0.f) ? s1 : LRELU_ALPHA * s1;
        float s2 = base + a_dst[d2]; s2 = (s2 > 0.f) ? s2 : LRELU_ALPHA * s2;
        float s3 = base + a_dst[d3]; s3 = (s3 > 0.f) ? s3 : LRELU_ALPHA * s3;
        const float x0 = expf(s0), x1 = expf(s1), x2 = expf(s2), x3 = expf(s3);
        acc.x += x0 * f0.x + x1 * f1.x + x2 * f2.x + x3 * f3.x;
        acc.y += x0 * f0.y + x1 * f1.y + x2 * f2.y + x3 * f3.y;
        acc.z += x0 * f0.z + x1 * f1.z + x2 * f2.z + x3 * f3.z;
        acc.w += x0 * f0.w + x1 * f1.w + x2 * f2.w + x3 * f3.w;
        dsum += x0 + x1 + x2 + x3;
    }
    for (; e < re; ++e) {
        const int d = dst[e];
        const float4 f = F4[(size_t)d * 64 + l];
        float s = base + a_dst[d]; s = (s > 0.f) ? s : LRELU_ALPHA * s;
        const float x = expf(s);
        acc.x += x * f.x; acc.y += x * f.y; acc.z += x * f.z; acc.w += x * f.w;
        dsum += x;
    }

    const float inv = (re > rs) ? 1.f / dsum : 0.f;  // wave-uniform
    float4 o;
    o.x = acc.x * inv; o.y = acc.y * inv; o.z = acc.z * inv; o.w = acc.w * inv;
    ((float4*)out)[(size_t)i * 64 + l] = o;
}

// ---------------------------------------------------------------------------
extern "C" void kernel_launch(void* const* d_in, const int* in_sizes, int n_in,
                              void* d_out, int out_size, void* d_ws, size_t ws_size,
                              hipStream_t stream) {
    const float* X     = (const float*)d_in[0];
    const int*   edges = (const int*)d_in[1];
    const float* W1    = (const float*)d_in[2];
    const float* b1    = (const float*)d_in[3];
    const float* Wa    = (const float*)d_in[4];
    const float* ba    = (const float*)d_in[5];
    float* out = (float*)d_out;

    // workspace carve-up (~11.6 MB of the ws)
    float* feats     = (float*)d_ws;                 // N*D fp32 (16B-aligned base)
    float* a_src     = feats + (size_t)N_NODES * D;  // N
    float* a_dst     = a_src + N_NODES;              // N
    int*   dstv      = (int*)(a_dst + N_NODES);      // E
    int*   row_start = dstv + E_EDGES;               // N+1

    prep<<<(E_EDGES + 255) / 256, 256, 0, stream>>>(edges, dstv, row_start);
    gemm_rowdots<<<N_NODES / GR, 256, 0, stream>>>(X, W1, b1, Wa, feats, a_src, a_dst);
    aggregate<<<N_NODES / 4, 256, 0, stream>>>(dstv, row_start, a_src, a_dst, ba, feats, out);
}

// Round 7
// 140.204 us; speedup vs baseline: 1.0319x; 1.0319x over previous
//
#include <hip/hip_runtime.h>
#include <hip/hip_bf16.h>

#define N_NODES 10000
#define E_EDGES 320000
#define D 256
#define LRELU_ALPHA 0.2f

// All float tensors fp32 (established round 3). Edges int32-or-int64 detect.
// dur_us includes harness re-poison fills (~56 us fixed) — round-6 forensics.

constexpr int GR = 8;  // GEMM rows per block (10000/8 = 1250 blocks, ~4.9/CU)

__device__ __forceinline__ float bu2f(unsigned short u) {
    return __uint_as_float((unsigned)u << 16);  // bf16 -> f32 exact
}

// ---------------------------------------------------------------------------
// K1: raw edges -> dst[] and CSR row_start[] in one pass. src is sorted.
// ---------------------------------------------------------------------------
__global__ __launch_bounds__(256) void prep(const int* __restrict__ raw,
                                            int* __restrict__ dst,
                                            int* __restrict__ row_start) {
    bool is64 = true;  // int64 rows: [s_lo, s_hi, d_lo, d_hi], hi words == 0
    #pragma unroll
    for (int t = 0; t < 16; ++t)
        if (raw[2 * t + 1] != 0) is64 = false;

    int e = blockIdx.x * 256 + threadIdx.x;
    if (e >= E_EDGES) return;
    int s, d, sprev;
    if (is64) { s = raw[4 * e]; d = raw[4 * e + 2]; sprev = e ? raw[4 * e - 4] : -1; }
    else      { s = raw[2 * e]; d = raw[2 * e + 1]; sprev = e ? raw[2 * e - 2] : -1; }
    dst[e] = d;
    for (int r = sprev + 1; r <= s; ++r) row_start[r] = e;
    if (e == E_EDGES - 1)
        for (int r = s + 1; r <= N_NODES; ++r) row_start[r] = E_EDGES;
}

// ---------------------------------------------------------------------------
// K2: feats = X @ W1 + b1; feats stored bf16 (for the gather kernel);
//     a_src/a_dst row-dots computed from the fp32 registers (exact).
// LDS-free: X addresses are wave-uniform (blockIdx + unrolled constants) ->
// compiler promotes to s_load_dwordx4; xs values live in SGPRs and feed
// v_fmac as the scalar operand. Kills the 33-us LDS broadcast-bus floor of
// rounds 4-6 (VALUBusy was 18.6% — 4 B LDS-delivered per FMA).
// W1[k*D+j] is per-thread, coalesced 256 B/wave, L2-resident.
// ---------------------------------------------------------------------------
__global__ __launch_bounds__(256) void gemm_rowdots(const float* __restrict__ X,
                                                    const float* __restrict__ W1,
                                                    const float* __restrict__ b1,
                                                    const float* __restrict__ Wa,
                                                    __hip_bfloat16* __restrict__ featsb,
                                                    float* __restrict__ a_src,
                                                    float* __restrict__ a_dst) {
    const int j = threadIdx.x;
    const int row0 = blockIdx.x * GR;
    const float* Xb = X + (size_t)row0 * D;  // wave-uniform base

    float acc[GR];
    #pragma unroll
    for (int r = 0; r < GR; ++r) acc[r] = 0.f;

    #pragma unroll 2
    for (int k0 = 0; k0 < D; k0 += 4) {
        float4 xr[GR];  // uniform loads -> SGPRs
        #pragma unroll
        for (int r = 0; r < GR; ++r)
            xr[r] = *(const float4*)(Xb + (size_t)r * D + k0);
        const float w0 = W1[(k0 + 0) * D + j];
        const float w1 = W1[(k0 + 1) * D + j];
        const float w2 = W1[(k0 + 2) * D + j];
        const float w3 = W1[(k0 + 3) * D + j];
        #pragma unroll
        for (int r = 0; r < GR; ++r) {
            acc[r] += xr[r].x * w0;
            acc[r] += xr[r].y * w1;
            acc[r] += xr[r].z * w2;
            acc[r] += xr[r].w * w3;
        }
    }

    const float bias = b1[j];
    const float wa1 = Wa[j], wa2 = Wa[D + j];
    #pragma unroll
    for (int r = 0; r < GR; ++r) acc[r] += bias;
    #pragma unroll
    for (int r = 0; r < GR; ++r)
        featsb[(size_t)(row0 + r) * D + j] = __float2bfloat16(acc[r]);

    // fused row-dots from fp32 accs: lanes hold distinct columns -> reduce
    __shared__ float red[2][4][GR];
    const int lane = j & 63, wv = j >> 6;
    #pragma unroll
    for (int r = 0; r < GR; ++r) {
        float p1 = acc[r] * wa1;
        float p2 = acc[r] * wa2;
        #pragma unroll
        for (int off = 32; off > 0; off >>= 1) {
            p1 += __shfl_down(p1, off);
            p2 += __shfl_down(p2, off);
        }
        if (lane == 0) { red[0][wv][r] = p1; red[1][wv][r] = p2; }
    }
    __syncthreads();
    if (j < 2 * GR) {
        const int dot = j >= GR, r = j & (GR - 1);
        float s = red[dot][0][r] + red[dot][1][r] + red[dot][2][r] + red[dot][3][r];
        (dot == 0 ? a_src : a_dst)[row0 + r] = s;
    }
}

// ---------------------------------------------------------------------------
// K3: one WAVE per node. Lane l owns cols 4l..4l+3 as bf16x4 (ushort4, 8 B
// per lane -> 512 B per wave-gather; feats table is 5 MB, ~L2-resident).
// All lanes walk the same edge list -> dsum and scale are wave-uniform (no
// lane reduce — round-4 lesson), no LDS, no syncthreads.
// ---------------------------------------------------------------------------
__global__ __launch_bounds__(256) void aggregate(const int* __restrict__ dst,
                                                 const int* __restrict__ row_start,
                                                 const float* __restrict__ a_src,
                                                 const float* __restrict__ a_dst,
                                                 const float* __restrict__ ba,
                                                 const unsigned short* __restrict__ featsb,
                                                 float* __restrict__ out) {
    const int i = blockIdx.x * 4 + (threadIdx.x >> 6);  // N_NODES % 4 == 0
    const int l = threadIdx.x & 63;
    const int rs = row_start[i], re = row_start[i + 1];
    const float base = a_src[i] + ba[0];
    const ushort4* F = (const ushort4*)featsb;  // row = 64 ushort4

    float4 acc = {0.f, 0.f, 0.f, 0.f};
    float dsum = 0.f;

    int e = rs;
    for (; e + 4 <= re; e += 4) {  // 4 independent 512 B gathers in flight
        const int d0 = dst[e], d1 = dst[e + 1], d2 = dst[e + 2], d3 = dst[e + 3];
        const ushort4 f0 = F[(size_t)d0 * 64 + l];
        const ushort4 f1 = F[(size_t)d1 * 64 + l];
        const ushort4 f2 = F[(size_t)d2 * 64 + l];
        const ushort4 f3 = F[(size_t)d3 * 64 + l];
        float s0 = base + a_dst[d0]; s0 = (s0 > 0.f) ? s0 : LRELU_ALPHA * s0;
        float s1 = base + a_dst[d1]; s1 = (s1 > 0.f) ? s1 : LRELU_ALPHA * s1;
        float s2 = base + a_dst[d2]; s2 = (s2 > 0.f) ? s2 : LRELU_ALPHA * s2;
        float s3 = base + a_dst[d3]; s3 = (s3 > 0.f) ? s3 : LRELU_ALPHA * s3;
        const float x0 = expf(s0), x1 = expf(s1), x2 = expf(s2), x3 = expf(s3);
        acc.x += x0 * bu2f(f0.x) + x1 * bu2f(f1.x) + x2 * bu2f(f2.x) + x3 * bu2f(f3.x);
        acc.y += x0 * bu2f(f0.y) + x1 * bu2f(f1.y) + x2 * bu2f(f2.y) + x3 * bu2f(f3.y);
        acc.z += x0 * bu2f(f0.z) + x1 * bu2f(f1.z) + x2 * bu2f(f2.z) + x3 * bu2f(f3.z);
        acc.w += x0 * bu2f(f0.w) + x1 * bu2f(f1.w) + x2 * bu2f(f2.w) + x3 * bu2f(f3.w);
        dsum += x0 + x1 + x2 + x3;
    }
    for (; e < re; ++e) {
        const int d = dst[e];
        const ushort4 f = F[(size_t)d * 64 + l];
        float s = base + a_dst[d]; s = (s > 0.f) ? s : LRELU_ALPHA * s;
        const float x = expf(s);
        acc.x += x * bu2f(f.x); acc.y += x * bu2f(f.y);
        acc.z += x * bu2f(f.z); acc.w += x * bu2f(f.w);
        dsum += x;
    }

    const float inv = (re > rs) ? 1.f / dsum : 0.f;  // wave-uniform
    float4 o;
    o.x = acc.x * inv; o.y = acc.y * inv; o.z = acc.z * inv; o.w = acc.w * inv;
    ((float4*)out)[(size_t)i * 64 + l] = o;
}

// ---------------------------------------------------------------------------
extern "C" void kernel_launch(void* const* d_in, const int* in_sizes, int n_in,
                              void* d_out, int out_size, void* d_ws, size_t ws_size,
                              hipStream_t stream) {
    const float* X     = (const float*)d_in[0];
    const int*   edges = (const int*)d_in[1];
    const float* W1    = (const float*)d_in[2];
    const float* b1    = (const float*)d_in[3];
    const float* Wa    = (const float*)d_in[4];
    const float* ba    = (const float*)d_in[5];
    float* out = (float*)d_out;

    // workspace carve-up (~7 MB)
    __hip_bfloat16* featsb = (__hip_bfloat16*)d_ws;        // N*D bf16 = 5.12 MB
    float* a_src     = (float*)(featsb + (size_t)N_NODES * D);  // N
    float* a_dst     = a_src + N_NODES;                    // N
    int*   dstv      = (int*)(a_dst + N_NODES);            // E
    int*   row_start = dstv + E_EDGES;                     // N+1

    prep<<<(E_EDGES + 255) / 256, 256, 0, stream>>>(edges, dstv, row_start);
    gemm_rowdots<<<N_NODES / GR, 256, 0, stream>>>(X, W1, b1, Wa, featsb, a_src, a_dst);
    aggregate<<<N_NODES / 4, 256, 0, stream>>>(dstv, row_start, a_src, a_dst, ba,
                                               (const unsigned short*)featsb, out);
}

// Round 8
// 112.076 us; speedup vs baseline: 1.2909x; 1.2510x over previous
//
#include <hip/hip_runtime.h>
#include <hip/hip_bf16.h>

#define N_NODES 10000
#define E_EDGES 320000
#define D 256
#define LRELU_ALPHA 0.2f

// fp32 world (round 3). dur_us includes ~56 us of harness re-poison fills
// (round-6 forensics). fp32 VALU GEMM floor ~45 us (rounds 5-7) -> MFMA.

using short8  = __attribute__((ext_vector_type(8))) short;
using floatx4 = __attribute__((ext_vector_type(4))) float;
using bf16 = __hip_bfloat16;

__device__ __forceinline__ float bu2f(unsigned short u) {
    return __uint_as_float((unsigned)u << 16);
}

// ---------------------------------------------------------------------------
// K1: raw edges -> dst[] and CSR row_start[] in one pass. src is sorted.
// ---------------------------------------------------------------------------
__global__ __launch_bounds__(256) void prep(const int* __restrict__ raw,
                                            int* __restrict__ dst,
                                            int* __restrict__ row_start) {
    bool is64 = true;  // int64 rows: [s_lo, s_hi, d_lo, d_hi], hi words == 0
    #pragma unroll
    for (int t = 0; t < 16; ++t)
        if (raw[2 * t + 1] != 0) is64 = false;

    int e = blockIdx.x * 256 + threadIdx.x;
    if (e >= E_EDGES) return;
    int s, d, sprev;
    if (is64) { s = raw[4 * e]; d = raw[4 * e + 2]; sprev = e ? raw[4 * e - 4] : -1; }
    else      { s = raw[2 * e]; d = raw[2 * e + 1]; sprev = e ? raw[2 * e - 2] : -1; }
    dst[e] = d;
    for (int r = sprev + 1; r <= s; ++r) row_start[r] = e;
    if (e == E_EDGES - 1)
        for (int r = s + 1; r <= N_NODES; ++r) row_start[r] = E_EDGES;
}

// ---------------------------------------------------------------------------
// K1b: X fp32 -> bf16 row-major (A-frag loads become direct 16 B reads).
// ---------------------------------------------------------------------------
__global__ __launch_bounds__(256) void xcast(const float* __restrict__ X,
                                             bf16* __restrict__ Xb) {
    const int i4 = blockIdx.x * 256 + threadIdx.x;  // 2.56M/4 = 640000 exact
    const float4 v = ((const float4*)X)[i4];
    bf16* o = Xb + (size_t)i4 * 4;
    o[0] = __float2bfloat16(v.x);
    o[1] = __float2bfloat16(v.y);
    o[2] = __float2bfloat16(v.z);
    o[3] = __float2bfloat16(v.w);
}

// ---------------------------------------------------------------------------
// K1c: W1 -> bf16 in MFMA B-fragment order.
// W1f[((s*16+t)*64+l)*8+j] = bf16(W1[k*D+n]), k = s*32+(l>>4)*8+j,
// n = t*16+(l&15)  — so a wave's B-frag for (k-step s, n-tile t) is one
// coalesced 16 B/lane load. [B layout n=lane&15, k=quad*8+j — m89-verified]
// ---------------------------------------------------------------------------
__global__ __launch_bounds__(256) void wprep(const float* __restrict__ W1,
                                             bf16* __restrict__ W1f) {
    const int id = blockIdx.x * 256 + threadIdx.x;  // 65536 exact
    const int j = id & 7, l = (id >> 3) & 63, t = (id >> 9) & 15, s = id >> 13;
    const int k = s * 32 + (l >> 4) * 8 + j;
    const int n = t * 16 + (l & 15);
    W1f[id] = __float2bfloat16(W1[k * D + n]);
}

// ---------------------------------------------------------------------------
// K2: feats = X @ W1 + b1 via v_mfma_f32_16x16x32_bf16, fp32 accumulate.
// 625 blocks x 16 rows (exact). Wave w owns cols 64w..64w+63 (4 n-tiles).
// 8 k-steps x 4 tiles = 32 MFMA/wave. Epilogue: +bias (fp32), store bf16
// feats, fused a_src/a_dst row-dots from fp32 accumulators.
// D layout: col=lane&15, row=quad*4+reg (m89/m91-verified).
// ---------------------------------------------------------------------------
__global__ __launch_bounds__(256) void gemm_mfma(const bf16* __restrict__ Xb,
                                                 const bf16* __restrict__ W1f,
                                                 const float* __restrict__ b1,
                                                 const float* __restrict__ Wa,
                                                 bf16* __restrict__ featsb,
                                                 float* __restrict__ a_src,
                                                 float* __restrict__ a_dst) {
    const int w = threadIdx.x >> 6, l = threadIdx.x & 63;
    const int quad = l >> 4, lan = l & 15;
    const int row0 = blockIdx.x * 16;

    floatx4 acc[4] = {{0.f, 0.f, 0.f, 0.f}, {0.f, 0.f, 0.f, 0.f},
                      {0.f, 0.f, 0.f, 0.f}, {0.f, 0.f, 0.f, 0.f}};

    // A-frags: lane reads X row (row0+lan), k = s*32 + quad*8 .. +7 (16 B)
    const short8* A8 = (const short8*)(Xb + (size_t)(row0 + lan) * D);
    const short8* B8 = (const short8*)W1f;

    #pragma unroll
    for (int s = 0; s < 8; ++s) {
        const short8 af = A8[s * 4 + quad];
        #pragma unroll
        for (int t = 0; t < 4; ++t) {
            const short8 bf = B8[(s * 16 + (4 * w + t)) * 64 + l];
            acc[t] = __builtin_amdgcn_mfma_f32_16x16x32_bf16(af, bf, acc[t], 0, 0, 0);
        }
    }

    // epilogue: lane l, tile t, reg r holds D[m][n], m=quad*4+r, n=(4w+t)*16+lan
    float p1[4] = {0.f, 0.f, 0.f, 0.f}, p2[4] = {0.f, 0.f, 0.f, 0.f};
    #pragma unroll
    for (int t = 0; t < 4; ++t) {
        const int n = (4 * w + t) * 16 + lan;
        const float bias = b1[n], wa1 = Wa[n], wa2 = Wa[D + n];
        #pragma unroll
        for (int r = 0; r < 4; ++r) {
            const float v = acc[t][r] + bias;
            featsb[(size_t)(row0 + quad * 4 + r) * D + n] = __float2bfloat16(v);
            p1[r] += v * wa1;
            p2[r] += v * wa2;
        }
    }

    // reduce across the 16 lanes of each quad (rows quad*4+r)
    __shared__ float red1[4][16], red2[4][16];
    #pragma unroll
    for (int r = 0; r < 4; ++r) {
        #pragma unroll
        for (int off = 1; off < 16; off <<= 1) {
            p1[r] += __shfl_xor(p1[r], off);
            p2[r] += __shfl_xor(p2[r], off);
        }
        if (lan == 0) { red1[w][quad * 4 + r] = p1[r]; red2[w][quad * 4 + r] = p2[r]; }
    }
    __syncthreads();
    if (threadIdx.x < 16) {
        const int m = threadIdx.x;
        a_src[row0 + m] = red1[0][m] + red1[1][m] + red1[2][m] + red1[3][m];
        a_dst[row0 + m] = red2[0][m] + red2[1][m] + red2[2][m] + red2[3][m];
    }
}

// ---------------------------------------------------------------------------
// K3: one WAVE per node; lane l owns cols 4l..4l+3 as bf16x4 (512 B/wave
// gather from the 5 MB feats table). dsum & scale wave-uniform (round-4
// lesson): no reduce, no LDS, no syncthreads.
// ---------------------------------------------------------------------------
__global__ __launch_bounds__(256) void aggregate(const int* __restrict__ dst,
                                                 const int* __restrict__ row_start,
                                                 const float* __restrict__ a_src,
                                                 const float* __restrict__ a_dst,
                                                 const float* __restrict__ ba,
                                                 const unsigned short* __restrict__ featsb,
                                                 float* __restrict__ out) {
    const int i = blockIdx.x * 4 + (threadIdx.x >> 6);  // N_NODES % 4 == 0
    const int l = threadIdx.x & 63;
    const int rs = row_start[i], re = row_start[i + 1];
    const float base = a_src[i] + ba[0];
    const ushort4* F = (const ushort4*)featsb;

    float4 acc = {0.f, 0.f, 0.f, 0.f};
    float dsum = 0.f;

    int e = rs;
    for (; e + 4 <= re; e += 4) {
        const int d0 = dst[e], d1 = dst[e + 1], d2 = dst[e + 2], d3 = dst[e + 3];
        const ushort4 f0 = F[(size_t)d0 * 64 + l];
        const ushort4 f1 = F[(size_t)d1 * 64 + l];
        const ushort4 f2 = F[(size_t)d2 * 64 + l];
        const ushort4 f3 = F[(size_t)d3 * 64 + l];
        float s0 = base + a_dst[d0]; s0 = (s0 > 0.f) ? s0 : LRELU_ALPHA * s0;
        float s1 = base + a_dst[d1]; s1 = (s1 > 0.f) ? s1 : LRELU_ALPHA * s1;
        float s2 = base + a_dst[d2]; s2 = (s2 > 0.f) ? s2 : LRELU_ALPHA * s2;
        float s3 = base + a_dst[d3]; s3 = (s3 > 0.f) ? s3 : LRELU_ALPHA * s3;
        const float x0 = expf(s0), x1 = expf(s1), x2 = expf(s2), x3 = expf(s3);
        acc.x += x0 * bu2f(f0.x) + x1 * bu2f(f1.x) + x2 * bu2f(f2.x) + x3 * bu2f(f3.x);
        acc.y += x0 * bu2f(f0.y) + x1 * bu2f(f1.y) + x2 * bu2f(f2.y) + x3 * bu2f(f3.y);
        acc.z += x0 * bu2f(f0.z) + x1 * bu2f(f1.z) + x2 * bu2f(f2.z) + x3 * bu2f(f3.z);
        acc.w += x0 * bu2f(f0.w) + x1 * bu2f(f1.w) + x2 * bu2f(f2.w) + x3 * bu2f(f3.w);
        dsum += x0 + x1 + x2 + x3;
    }
    for (; e < re; ++e) {
        const int d = dst[e];
        const ushort4 f = F[(size_t)d * 64 + l];
        float s = base + a_dst[d]; s = (s > 0.f) ? s : LRELU_ALPHA * s;
        const float x = expf(s);
        acc.x += x * bu2f(f.x); acc.y += x * bu2f(f.y);
        acc.z += x * bu2f(f.z); acc.w += x * bu2f(f.w);
        dsum += x;
    }

    const float inv = (re > rs) ? 1.f / dsum : 0.f;  // wave-uniform
    float4 o;
    o.x = acc.x * inv; o.y = acc.y * inv; o.z = acc.z * inv; o.w = acc.w * inv;
    ((float4*)out)[(size_t)i * 64 + l] = o;
}

// ---------------------------------------------------------------------------
extern "C" void kernel_launch(void* const* d_in, const int* in_sizes, int n_in,
                              void* d_out, int out_size, void* d_ws, size_t ws_size,
                              hipStream_t stream) {
    const float* X     = (const float*)d_in[0];
    const int*   edges = (const int*)d_in[1];
    const float* W1    = (const float*)d_in[2];
    const float* b1    = (const float*)d_in[3];
    const float* Wa    = (const float*)d_in[4];
    const float* ba    = (const float*)d_in[5];
    float* out = (float*)d_out;

    // workspace carve-up (~14 MB), all 16 B aligned
    bf16* featsb = (bf16*)d_ws;                            // N*D bf16 = 5.12 MB
    bf16* Xb     = featsb + (size_t)N_NODES * D;           // N*D bf16 = 5.12 MB
    bf16* W1f    = Xb + (size_t)N_NODES * D;               // 64K bf16 = 128 KB
    float* a_src = (float*)(W1f + 65536);                  // N
    float* a_dst = a_src + N_NODES;                        // N
    int*   dstv  = (int*)(a_dst + N_NODES);                // E
    int*   row_start = dstv + E_EDGES;                     // N+1

    prep<<<(E_EDGES + 255) / 256, 256, 0, stream>>>(edges, dstv, row_start);
    xcast<<<(N_NODES * D / 4) / 256, 256, 0, stream>>>(X, Xb);
    wprep<<<65536 / 256, 256, 0, stream>>>(W1, W1f);
    gemm_mfma<<<N_NODES / 16, 256, 0, stream>>>(Xb, W1f, b1, Wa, featsb, a_src, a_dst);
    aggregate<<<N_NODES / 4, 256, 0, stream>>>(dstv, row_start, a_src, a_dst, ba,
                                               (const unsigned short*)featsb, out);
}